// Round 13
// baseline (99.461 us; speedup 1.0000x reference)
//
#include <hip/hip_runtime.h>
#include <hip/hip_bf16.h>

typedef unsigned short u16;
typedef __attribute__((ext_vector_type(8))) short short8;
typedef __attribute__((ext_vector_type(4))) float f32x4;

#define B_ 32
#define L_ 1024
#define D_ 1024
#define E_ 100
#define E1_ 101
#define M2_ (B_ * E1_)     // 3232 entity rows (incl. none-entity)
#define M2P_ 3328          // padded to 52*64 for MFMA tiles
#define QBLK_ 16           // rows per scores block
#define NT3_ 13            // ceil(Q_MAX=200 / 16) tiles that can contain valid rows
#define ZROW0_ (NT3_ * QBLK_)  // 208: first always-masked row
#define NZF_ 640               // zerofill blocks (20 per batch)
#define NPREP_ (M2_ + 1024 + NZF_)

#define MFMA16(a, b, c) __builtin_amdgcn_mfma_f32_16x16x32_bf16((a), (b), (c), 0, 0, 0)

__device__ __forceinline__ void split2(float x, u16& h, u16& l) {
    __hip_bfloat16 bh = __float2bfloat16(x);          // RN
    float r = x - __bfloat162float(bh);
    __hip_bfloat16 bl = __float2bfloat16(r);
    h = __builtin_bit_cast(u16, bh);
    l = __builtin_bit_cast(u16, bl);
}

// async global->LDS, 16B per lane; LDS dest = wave-uniform base + lane*16
__device__ __forceinline__ void gload16(const void* g, void* l) {
    __builtin_amdgcn_global_load_lds(
        (const __attribute__((address_space(1))) unsigned int*)g,
        (__attribute__((address_space(3))) unsigned int*)l, 16, 0, 0);
}

// ---------------- K1: flat fusion of [encode | wsplit | zerofill] (all independent)
__global__ __launch_bounds__(256) void k_prep(const float* __restrict__ q_enc,
                                              const float* __restrict__ none_ent,
                                              const float* __restrict__ W,
                                              const float* __restrict__ bias,
                                              const int* __restrict__ ranges,
                                              u16* __restrict__ enc_hi, u16* __restrict__ enc_lo,
                                              u16* __restrict__ w_hi, u16* __restrict__ w_lo,
                                              float* __restrict__ ep_last,
                                              float* __restrict__ co_att) {
    __shared__ float red4[4];
    int u = blockIdx.x;
    int t = threadIdx.x, c = t * 4;
    if (u < M2_) {
        // ---- encode unit: one (b, e) entity row
        int b = u / E1_, e = u - b * E1_;
        float4 acc;
        if (e == E_) {
            acc = *(const float4*)&none_ent[c];
        } else {
            acc = make_float4(0.f, 0.f, 0.f, 0.f);
            int r0 = ranges[(b * E_ + e) * 2 + 0];
            int r1 = ranges[(b * E_ + e) * 2 + 1];
            for (int l = r0 + 1; l < r1; ++l) {
                float4 v = *(const float4*)&q_enc[((size_t)b * L_ + l) * D_ + c];
                acc.x += v.x; acc.y += v.y; acc.z += v.z; acc.w += v.w;
            }
        }
        union { u16 uu[4]; float2 f; } ph, pl;
        split2(acc.x, ph.uu[0], pl.uu[0]); split2(acc.y, ph.uu[1], pl.uu[1]);
        split2(acc.z, ph.uu[2], pl.uu[2]); split2(acc.w, ph.uu[3], pl.uu[3]);
        *(float2*)&enc_hi[(size_t)u * 1024 + c] = ph.f;
        *(float2*)&enc_lo[(size_t)u * 1024 + c] = pl.f;
        const float* w1k = W + (size_t)1024 * 1024;
        float4 wv = *(const float4*)&w1k[c];
        float s = acc.x * wv.x + acc.y * wv.y + acc.z * wv.z + acc.w * wv.w;
        #pragma unroll
        for (int off = 32; off; off >>= 1) s += __shfl_down(s, off);
        if ((t & 63) == 0) red4[t >> 6] = s;
        __syncthreads();
        if (t == 0) ep_last[u] = red4[0] + red4[1] + red4[2] + red4[3] + bias[1024];
    } else if (u < M2_ + 1024) {
        // ---- wsplit unit: one W row
        int r = u - M2_;
        float4 v = *(const float4*)&W[(size_t)r * 1024 + c];
        union { u16 uu[4]; float2 f; } ph, pl;
        split2(v.x, ph.uu[0], pl.uu[0]); split2(v.y, ph.uu[1], pl.uu[1]);
        split2(v.z, ph.uu[2], pl.uu[2]); split2(v.w, ph.uu[3], pl.uu[3]);
        *(float2*)&w_hi[(size_t)r * 1024 + c] = ph.f;
        *(float2*)&w_lo[(size_t)r * 1024 + c] = pl.f;
    } else {
        // ---- zerofill unit: 1/20th of one batch's always-masked co_att rows
        int zu = u - M2_ - 1024;          // 0..639
        int b = zu / 20, part = zu % 20;
        float4* base = (float4*)&co_att[((size_t)b * L_ + ZROW0_) * E1_];
        const int n4 = (L_ - ZROW0_) * E1_ / 4;   // 816*101/4 = 20604
        float4 z = make_float4(0.f, 0.f, 0.f, 0.f);
        for (int i = part * 256 + t; i < n4; i += 20 * 256)
            base[i] = z;
    }
}

// ---------------- K2: ep = enc . W^T + bias, 3-term bf16 MFMA
// 64x64 tile -> grid (16,52) = 832 blocks, LDS 32KB, launch_bounds(256,4).
__global__ __launch_bounds__(256, 4) void k_entproj(const u16* __restrict__ A_hi, const u16* __restrict__ A_lo,
                                                    const u16* __restrict__ B_hi, const u16* __restrict__ B_lo,
                                                    const float* __restrict__ bias,
                                                    u16* __restrict__ ep_hi, u16* __restrict__ ep_lo) {
    __shared__ __attribute__((aligned(16))) u16 Ah[64 * 64], Al[64 * 64], Bh[64 * 64], Bl[64 * 64];
    int tid = threadIdx.x;
    int m0 = blockIdx.y * 64, n0 = blockIdx.x * 64;
    int w = tid >> 6, lane = tid & 63, lr = lane & 15, lg = lane >> 4;
    int wr = w >> 1, wc = w & 1;
    f32x4 zero = {0.f, 0.f, 0.f, 0.f};
    f32x4 acc[2][2] = {{zero, zero}, {zero, zero}};
    for (int k0 = 0; k0 < 1024; k0 += 64) {
        // 512 slots per array (64 rows x 8 sgroups); per wave 128 slots (2 j-iters)
        #pragma unroll
        for (int j = 0; j < 2; ++j) {
            int slot = w * 128 + j * 64 + lane;   // slot = r*8 + s
            int r = slot >> 3, s = slot & 7;
            int g = (s ^ (r & 7)) << 3;           // pre-swizzled source column group
            size_t ga = (size_t)(m0 + r) * 1024 + k0 + g;
            size_t gb = (size_t)(n0 + r) * 1024 + k0 + g;
            int ld = (w * 128 + j * 64) * 8;      // wave-uniform LDS base (u16 idx)
            gload16(&A_hi[ga], &Ah[ld]);
            gload16(&A_lo[ga], &Al[ld]);
            gload16(&B_hi[gb], &Bh[ld]);
            gload16(&B_lo[gb], &Bl[ld]);
        }
        __syncthreads();
        #pragma unroll
        for (int half = 0; half < 2; ++half) {
            int sk = half * 4 + lg;
            short8 a_h[2], a_l[2], b_h[2], b_l[2];
            #pragma unroll
            for (int mf = 0; mf < 2; ++mf) {
                int R = wr * 32 + mf * 16 + lr;
                int ad = R * 64 + ((sk ^ (R & 7)) << 3);
                a_h[mf] = __builtin_bit_cast(short8, *(const float4*)&Ah[ad]);
                a_l[mf] = __builtin_bit_cast(short8, *(const float4*)&Al[ad]);
            }
            #pragma unroll
            for (int nf = 0; nf < 2; ++nf) {
                int R = wc * 32 + nf * 16 + lr;
                int ad = R * 64 + ((sk ^ (R & 7)) << 3);
                b_h[nf] = __builtin_bit_cast(short8, *(const float4*)&Bh[ad]);
                b_l[nf] = __builtin_bit_cast(short8, *(const float4*)&Bl[ad]);
            }
            #pragma unroll
            for (int mf = 0; mf < 2; ++mf)
                #pragma unroll
                for (int nf = 0; nf < 2; ++nf) {
                    acc[mf][nf] = MFMA16(a_h[mf], b_h[nf], acc[mf][nf]);
                    acc[mf][nf] = MFMA16(a_h[mf], b_l[nf], acc[mf][nf]);
                    acc[mf][nf] = MFMA16(a_l[mf], b_h[nf], acc[mf][nf]);
                }
        }
        __syncthreads();
    }
    #pragma unroll
    for (int mf = 0; mf < 2; ++mf)
        #pragma unroll
        for (int nf = 0; nf < 2; ++nf)
            #pragma unroll
            for (int reg = 0; reg < 4; ++reg) {
                int m = m0 + wr * 32 + mf * 16 + lg * 4 + reg;
                if (m < M2_) {
                    int n = n0 + wc * 32 + nf * 16 + lr;
                    float v = acc[mf][nf][reg] + bias[n];
                    u16 h, l;
                    split2(v, h, l);
                    ep_hi[(size_t)m * 1024 + n] = h;
                    ep_lo[(size_t)m * 1024 + n] = l;
                }
            }
}

// ---------------- K3: scores, reg-direct operands (NO LDS staging, NO K-loop barriers)
// flat grid 416: b = id&31 -> XCD = b%8 (ep panel L2-local). Each wave loads its
// A-frag (q fp32, split in-register) and B-frags (ep hi/lo short8) straight from
// global/L2; K-loop enumeration matches the old (k0,ks) order bit-exactly.
__global__ __launch_bounds__(256, 4) void k_scores(const float* __restrict__ q_enc,
                                                   const float* __restrict__ hint,
                                                   const u16* __restrict__ ep_hi, const u16* __restrict__ ep_lo,
                                                   const float* __restrict__ ep_last,
                                                   const int* __restrict__ qlen,
                                                   float* __restrict__ co_att,
                                                   float* __restrict__ partial) {
    __shared__ float Ss[16 * 113];
    __shared__ float red[QBLK_][16];
    int id = blockIdx.x;
    int b = id & 31, mt = id >> 5, l0 = mt * QBLK_;
    int tid = threadIdx.x;
    int qn = qlen[b];
    if (l0 >= qn) {
        // masked tile: zero co_att rows + zero partial
        float* base = &co_att[((size_t)b * L_ + l0) * E1_];
        float4 z = make_float4(0.f, 0.f, 0.f, 0.f);
        for (int i = tid; i < QBLK_ * E1_ / 4; i += 256)
            *(float4*)&base[i * 4] = z;
        for (int e = tid; e < E1_; e += 256)
            partial[((size_t)b * NT3_ + mt) * E1_ + e] = 0.f;
        return;
    }
    int w = tid >> 6, lane = tid & 63, lr = lane & 15, lg = lane >> 4;
    int nb = w * 2, nc = (w == 3) ? 1 : 2;    // frags nb..nb+nc-1
    f32x4 zero = {0.f, 0.f, 0.f, 0.f};
    f32x4 acc[2] = {zero, zero};
    const float* qrow = &q_enc[((size_t)b * L_ + l0 + lr) * D_ + lg * 8];
    const u16* eph0 = &ep_hi[((size_t)b * E1_ + nb * 16 + lr) * 1024 + lg * 8];
    const u16* epl0 = &ep_lo[((size_t)b * E1_ + nb * 16 + lr) * 1024 + lg * 8];
    #pragma unroll 4
    for (int t = 0; t < 32; ++t) {
        int k = t * 32;
        // A-frag: q fp32 -> hi/lo bf16 in-register (same k enumeration as LDS path)
        float4 x0 = *(const float4*)(qrow + k);
        float4 x1 = *(const float4*)(qrow + k + 4);
        float xs[8] = {x0.x, x0.y, x0.z, x0.w, x1.x, x1.y, x1.z, x1.w};
        short8 ah, al;
        #pragma unroll
        for (int j = 0; j < 8; ++j) {
            u16 hh, ll;
            split2(xs[j], hh, ll);
            ah[j] = (short)hh; al[j] = (short)ll;
        }
        #pragma unroll
        for (int nf = 0; nf < 2; ++nf) {
            if (nf < nc) {
                short8 bh = *(const short8*)(eph0 + (size_t)nf * 16 * 1024 + k);
                short8 bl = *(const short8*)(epl0 + (size_t)nf * 16 * 1024 + k);
                acc[nf] = MFMA16(ah, bh, acc[nf]);
                acc[nf] = MFMA16(ah, bl, acc[nf]);
                acc[nf] = MFMA16(al, bh, acc[nf]);
            }
        }
    }
    // dump score frags: row = lg*4 + reg, col = (nb+nf)*16 + lr  (single handoff barrier)
    #pragma unroll
    for (int nf = 0; nf < 2; ++nf)
        if (nf < nc) {
            #pragma unroll
            for (int reg = 0; reg < 4; ++reg)
                Ss[(lg * 4 + reg) * 113 + (nb + nf) * 16 + lr] = acc[nf][reg];
        }
    __syncthreads();
    // ---- softmax over 101 entities per row: 16 rows x 16 entity-groups
    int l = tid & 15, eg = tid >> 4;
    float h = hint[(size_t)b * L_ + l0 + l];
    float sc[7];
    #pragma unroll
    for (int j = 0; j < 7; ++j) {
        int e = eg + 16 * j;
        sc[j] = (e < E1_) ? (Ss[l * 113 + e] + h * ep_last[b * E1_ + e]) : -3.4e38f;
    }
    float mloc = -3.4e38f;
    #pragma unroll
    for (int j = 0; j < 7; ++j) mloc = fmaxf(mloc, sc[j]);
    red[l][eg] = mloc;
    __syncthreads();
    float m = red[l][0];
    #pragma unroll
    for (int k = 1; k < 16; ++k) m = fmaxf(m, red[l][k]);
    __syncthreads();
    float p[7];
    float sloc = 0.f;
    #pragma unroll
    for (int j = 0; j < 7; ++j) {
        p[j] = 0.f;
        if (eg + 16 * j < E1_) { p[j] = __expf(sc[j] - m); sloc += p[j]; }
    }
    red[l][eg] = sloc;
    __syncthreads();
    float ssum = 0.f;
    #pragma unroll
    for (int k = 0; k < 16; ++k) ssum += red[l][k];
    float inv = 1.f / ssum;
    bool valid = (l0 + l) < qn;
    float maskv = valid ? inv : 0.f;
    float* row = &co_att[((size_t)b * L_ + l0 + l) * E1_];
    #pragma unroll
    for (int j = 0; j < 7; ++j) {
        int e = eg + 16 * j;
        if (e < E1_) row[e] = p[j] * maskv;
    }
    // partial att: sum over this tile's valid rows (16-lane group reduce over l)
    #pragma unroll
    for (int j = 0; j < 7; ++j) {
        int e = eg + 16 * j;
        float v = (e < E1_) ? p[j] * maskv : 0.f;
        v += __shfl_xor(v, 1);  v += __shfl_xor(v, 2);
        v += __shfl_xor(v, 4);  v += __shfl_xor(v, 8);
        if ((tid & 15) == 0 && e < E1_)
            partial[((size_t)b * NT3_ + mt) * E1_ + e] = v;
    }
}

// ---------------- K4: att[b,e] = min(sum of partials, 1)
__global__ __launch_bounds__(256) void k_final(const float* __restrict__ partial,
                                               float* __restrict__ att) {
    int i = blockIdx.x * 256 + threadIdx.x;
    if (i >= B_ * E_) return;
    int b = i / E_, e = i % E_;
    float s = 0.f;
    #pragma unroll
    for (int k = 0; k < NT3_; ++k) s += partial[((size_t)b * NT3_ + k) * E1_ + e];
    att[i] = fminf(s, 1.f);
}

extern "C" void kernel_launch(void* const* d_in, const int* in_sizes, int n_in,
                              void* d_out, int out_size, void* d_ws, size_t ws_size,
                              hipStream_t stream) {
    const float* q_enc    = (const float*)d_in[0];
    const float* hint     = (const float*)d_in[1];
    const float* W        = (const float*)d_in[2];
    const float* bias     = (const float*)d_in[3];
    const float* none_ent = (const float*)d_in[4];
    const int*   qlen     = (const int*)d_in[5];
    const int*   ranges   = (const int*)d_in[6];

    float* att    = (float*)d_out;
    float* co_att = att + (size_t)B_ * E_;

    u16* enc_hi = (u16*)d_ws;
    u16* enc_lo = enc_hi + (size_t)M2P_ * 1024;
    u16* w_hi   = enc_lo + (size_t)M2P_ * 1024;
    u16* w_lo   = w_hi + (size_t)1024 * 1024;
    u16* ep_hi  = w_lo + (size_t)1024 * 1024;
    u16* ep_lo  = ep_hi + (size_t)M2P_ * 1024;
    float* ep_last = (float*)(ep_lo + (size_t)M2P_ * 1024);
    float* part    = ep_last + M2P_;

    k_prep<<<NPREP_, 256, 0, stream>>>(q_enc, none_ent, W, bias, ranges,
                                       enc_hi, enc_lo, w_hi, w_lo, ep_last, co_att);
    k_entproj<<<dim3(16, 52), 256, 0, stream>>>(enc_hi, enc_lo, w_hi, w_lo, bias, ep_hi, ep_lo);
    k_scores<<<B_ * NT3_, 256, 0, stream>>>(q_enc, hint, ep_hi, ep_lo, ep_last, qlen, co_att, part);
    k_final<<<13, 256, 0, stream>>>(part, att);
}

// Round 14
// 91.337 us; speedup vs baseline: 1.0889x; 1.0889x over previous
//
#include <hip/hip_runtime.h>
#include <hip/hip_bf16.h>

typedef unsigned short u16;
typedef __attribute__((ext_vector_type(8))) short short8;
typedef __attribute__((ext_vector_type(4))) float f32x4;

#define B_ 32
#define L_ 1024
#define D_ 1024
#define E_ 100
#define E1_ 101
#define M2_ (B_ * E1_)     // 3232 entity rows (incl. none-entity)
#define M2P_ 3328          // padded to 52*64 for MFMA tiles
#define QBLK_ 16           // rows per scores block
#define NT3_ 13            // ceil(Q_MAX=200 / 16) tiles that can contain valid rows
#define ZROW0_ (NT3_ * QBLK_)  // 208: first always-masked row
#define NZF_ 640               // zerofill blocks (20 per batch)
#define NPREP_ (M2_ + 1024 + NZF_)

#define MFMA16(a, b, c) __builtin_amdgcn_mfma_f32_16x16x32_bf16((a), (b), (c), 0, 0, 0)

__device__ __forceinline__ void split2(float x, u16& h, u16& l) {
    __hip_bfloat16 bh = __float2bfloat16(x);          // RN
    float r = x - __bfloat162float(bh);
    __hip_bfloat16 bl = __float2bfloat16(r);
    h = __builtin_bit_cast(u16, bh);
    l = __builtin_bit_cast(u16, bl);
}

// async global->LDS, 16B per lane; LDS dest = wave-uniform base + lane*16
__device__ __forceinline__ void gload16(const void* g, void* l) {
    __builtin_amdgcn_global_load_lds(
        (const __attribute__((address_space(1))) unsigned int*)g,
        (__attribute__((address_space(3))) unsigned int*)l, 16, 0, 0);
}

// ---------------- K1: flat fusion of [encode | wsplit | zerofill] (all independent)
__global__ __launch_bounds__(256) void k_prep(const float* __restrict__ q_enc,
                                              const float* __restrict__ none_ent,
                                              const float* __restrict__ W,
                                              const float* __restrict__ bias,
                                              const int* __restrict__ ranges,
                                              u16* __restrict__ enc_hi, u16* __restrict__ enc_lo,
                                              u16* __restrict__ w_hi, u16* __restrict__ w_lo,
                                              float* __restrict__ ep_last,
                                              float* __restrict__ co_att) {
    __shared__ float red4[4];
    int u = blockIdx.x;
    int t = threadIdx.x, c = t * 4;
    if (u < M2_) {
        // ---- encode unit: one (b, e) entity row
        int b = u / E1_, e = u - b * E1_;
        float4 acc;
        if (e == E_) {
            acc = *(const float4*)&none_ent[c];
        } else {
            acc = make_float4(0.f, 0.f, 0.f, 0.f);
            int r0 = ranges[(b * E_ + e) * 2 + 0];
            int r1 = ranges[(b * E_ + e) * 2 + 1];
            for (int l = r0 + 1; l < r1; ++l) {
                float4 v = *(const float4*)&q_enc[((size_t)b * L_ + l) * D_ + c];
                acc.x += v.x; acc.y += v.y; acc.z += v.z; acc.w += v.w;
            }
        }
        union { u16 uu[4]; float2 f; } ph, pl;
        split2(acc.x, ph.uu[0], pl.uu[0]); split2(acc.y, ph.uu[1], pl.uu[1]);
        split2(acc.z, ph.uu[2], pl.uu[2]); split2(acc.w, ph.uu[3], pl.uu[3]);
        *(float2*)&enc_hi[(size_t)u * 1024 + c] = ph.f;
        *(float2*)&enc_lo[(size_t)u * 1024 + c] = pl.f;
        const float* w1k = W + (size_t)1024 * 1024;
        float4 wv = *(const float4*)&w1k[c];
        float s = acc.x * wv.x + acc.y * wv.y + acc.z * wv.z + acc.w * wv.w;
        #pragma unroll
        for (int off = 32; off; off >>= 1) s += __shfl_down(s, off);
        if ((t & 63) == 0) red4[t >> 6] = s;
        __syncthreads();
        if (t == 0) ep_last[u] = red4[0] + red4[1] + red4[2] + red4[3] + bias[1024];
    } else if (u < M2_ + 1024) {
        // ---- wsplit unit: one W row
        int r = u - M2_;
        float4 v = *(const float4*)&W[(size_t)r * 1024 + c];
        union { u16 uu[4]; float2 f; } ph, pl;
        split2(v.x, ph.uu[0], pl.uu[0]); split2(v.y, ph.uu[1], pl.uu[1]);
        split2(v.z, ph.uu[2], pl.uu[2]); split2(v.w, ph.uu[3], pl.uu[3]);
        *(float2*)&w_hi[(size_t)r * 1024 + c] = ph.f;
        *(float2*)&w_lo[(size_t)r * 1024 + c] = pl.f;
    } else {
        // ---- zerofill unit: 1/20th of one batch's always-masked co_att rows
        int zu = u - M2_ - 1024;          // 0..639
        int b = zu / 20, part = zu % 20;
        float4* base = (float4*)&co_att[((size_t)b * L_ + ZROW0_) * E1_];
        const int n4 = (L_ - ZROW0_) * E1_ / 4;   // 816*101/4 = 20604
        float4 z = make_float4(0.f, 0.f, 0.f, 0.f);
        for (int i = part * 256 + t; i < n4; i += 20 * 256)
            base[i] = z;
    }
}

// ---------------- K2: ep = enc . W^T + bias, 3-term bf16 MFMA
// 64x64 tile -> grid (16,52) = 832 blocks, LDS 32KB, launch_bounds(256,4).
__global__ __launch_bounds__(256, 4) void k_entproj(const u16* __restrict__ A_hi, const u16* __restrict__ A_lo,
                                                    const u16* __restrict__ B_hi, const u16* __restrict__ B_lo,
                                                    const float* __restrict__ bias,
                                                    u16* __restrict__ ep_hi, u16* __restrict__ ep_lo) {
    __shared__ __attribute__((aligned(16))) u16 Ah[64 * 64], Al[64 * 64], Bh[64 * 64], Bl[64 * 64];
    int tid = threadIdx.x;
    int m0 = blockIdx.y * 64, n0 = blockIdx.x * 64;
    int w = tid >> 6, lane = tid & 63, lr = lane & 15, lg = lane >> 4;
    int wr = w >> 1, wc = w & 1;
    f32x4 zero = {0.f, 0.f, 0.f, 0.f};
    f32x4 acc[2][2] = {{zero, zero}, {zero, zero}};
    for (int k0 = 0; k0 < 1024; k0 += 64) {
        // 512 slots per array (64 rows x 8 sgroups); per wave 128 slots (2 j-iters)
        #pragma unroll
        for (int j = 0; j < 2; ++j) {
            int slot = w * 128 + j * 64 + lane;   // slot = r*8 + s
            int r = slot >> 3, s = slot & 7;
            int g = (s ^ (r & 7)) << 3;           // pre-swizzled source column group
            size_t ga = (size_t)(m0 + r) * 1024 + k0 + g;
            size_t gb = (size_t)(n0 + r) * 1024 + k0 + g;
            int ld = (w * 128 + j * 64) * 8;      // wave-uniform LDS base (u16 idx)
            gload16(&A_hi[ga], &Ah[ld]);
            gload16(&A_lo[ga], &Al[ld]);
            gload16(&B_hi[gb], &Bh[ld]);
            gload16(&B_lo[gb], &Bl[ld]);
        }
        __syncthreads();
        #pragma unroll
        for (int half = 0; half < 2; ++half) {
            int sk = half * 4 + lg;
            short8 a_h[2], a_l[2], b_h[2], b_l[2];
            #pragma unroll
            for (int mf = 0; mf < 2; ++mf) {
                int R = wr * 32 + mf * 16 + lr;
                int ad = R * 64 + ((sk ^ (R & 7)) << 3);
                a_h[mf] = __builtin_bit_cast(short8, *(const float4*)&Ah[ad]);
                a_l[mf] = __builtin_bit_cast(short8, *(const float4*)&Al[ad]);
            }
            #pragma unroll
            for (int nf = 0; nf < 2; ++nf) {
                int R = wc * 32 + nf * 16 + lr;
                int ad = R * 64 + ((sk ^ (R & 7)) << 3);
                b_h[nf] = __builtin_bit_cast(short8, *(const float4*)&Bh[ad]);
                b_l[nf] = __builtin_bit_cast(short8, *(const float4*)&Bl[ad]);
            }
            #pragma unroll
            for (int mf = 0; mf < 2; ++mf)
                #pragma unroll
                for (int nf = 0; nf < 2; ++nf) {
                    acc[mf][nf] = MFMA16(a_h[mf], b_h[nf], acc[mf][nf]);
                    acc[mf][nf] = MFMA16(a_h[mf], b_l[nf], acc[mf][nf]);
                    acc[mf][nf] = MFMA16(a_l[mf], b_h[nf], acc[mf][nf]);
                }
        }
        __syncthreads();
    }
    #pragma unroll
    for (int mf = 0; mf < 2; ++mf)
        #pragma unroll
        for (int nf = 0; nf < 2; ++nf)
            #pragma unroll
            for (int reg = 0; reg < 4; ++reg) {
                int m = m0 + wr * 32 + mf * 16 + lg * 4 + reg;
                if (m < M2_) {
                    int n = n0 + wc * 32 + nf * 16 + lr;
                    float v = acc[mf][nf][reg] + bias[n];
                    u16 h, l;
                    split2(v, h, l);
                    ep_hi[(size_t)m * 1024 + n] = h;
                    ep_lo[(size_t)m * 1024 + n] = l;
                }
            }
}

// ---------------- K3: scores hybrid — A staged in LDS (shared split, coalesced),
// B (ep hi/lo) loaded reg-direct from L2 (wave-exclusive rows, no reuse).
// Removes all global_load_lds -> no vmcnt(0) drain coupling at barriers.
// flat grid 416: b = id&31 -> XCD = b%8 (ep panel L2-local, round-12 swizzle).
// K-enumeration matches round-12 staged path bit-exactly.
__global__ __launch_bounds__(256, 3) void k_scores(const float* __restrict__ q_enc,
                                                   const float* __restrict__ hint,
                                                   const u16* __restrict__ ep_hi, const u16* __restrict__ ep_lo,
                                                   const float* __restrict__ ep_last,
                                                   const int* __restrict__ qlen,
                                                   float* __restrict__ co_att,
                                                   float* __restrict__ partial) {
    __shared__ __attribute__((aligned(16))) u16 Ah[16 * 64], Al[16 * 64];
    __shared__ float Ss[16 * 113];
    __shared__ float red[QBLK_][16];
    int id = blockIdx.x;
    int b = id & 31, mt = id >> 5, l0 = mt * QBLK_;
    int tid = threadIdx.x;
    int qn = qlen[b];
    if (l0 >= qn) {
        // masked tile: zero co_att rows + zero partial
        float* base = &co_att[((size_t)b * L_ + l0) * E1_];
        float4 z = make_float4(0.f, 0.f, 0.f, 0.f);
        for (int i = tid; i < QBLK_ * E1_ / 4; i += 256)
            *(float4*)&base[i * 4] = z;
        for (int e = tid; e < E1_; e += 256)
            partial[((size_t)b * NT3_ + mt) * E1_ + e] = 0.f;
        return;
    }
    int w = tid >> 6, lane = tid & 63, lr = lane & 15, lg = lane >> 4;
    int nb = w * 2, nc = (w == 3) ? 1 : 2;    // frags nb..nb+nc-1
    f32x4 zero = {0.f, 0.f, 0.f, 0.f};
    f32x4 acc[2] = {zero, zero};
    const u16* eph0 = &ep_hi[((size_t)b * E1_ + nb * 16 + lr) * 1024 + lg * 8];
    const u16* epl0 = &ep_lo[((size_t)b * E1_ + nb * 16 + lr) * 1024 + lg * 8];
    for (int k0 = 0; k0 < 1024; k0 += 64) {
        if (tid < 128) {  // A: 16 rows x 64 k, split fp32 -> hi/lo on the fly (as round 12)
            int r = tid >> 3, s = tid & 7;
            const float* src = &q_enc[((size_t)b * L_ + l0 + r) * D_ + k0 + s * 8];
            float4 x0 = *(const float4*)src, x1 = *(const float4*)(src + 4);
            float xs[8] = {x0.x, x0.y, x0.z, x0.w, x1.x, x1.y, x1.z, x1.w};
            short8 hv, lv;
            #pragma unroll
            for (int j = 0; j < 8; ++j) {
                u16 hh, ll;
                split2(xs[j], hh, ll);
                hv[j] = (short)hh; lv[j] = (short)ll;
            }
            int dst = r * 64 + ((s ^ (r & 7)) << 3);
            *(float4*)&Ah[dst] = __builtin_bit_cast(float4, hv);
            *(float4*)&Al[dst] = __builtin_bit_cast(float4, lv);
        }
        __syncthreads();
        #pragma unroll
        for (int ks = 0; ks < 2; ++ks) {
            int sk = ks * 4 + lg;
            int adA = lr * 64 + ((sk ^ (lr & 7)) << 3);
            short8 ah = __builtin_bit_cast(short8, *(const float4*)&Ah[adA]);
            short8 al = __builtin_bit_cast(short8, *(const float4*)&Al[adA]);
            int kk = k0 + ks * 32;   // B frag cols kk + lg*8 (bit-identical enumeration)
            #pragma unroll
            for (int nf = 0; nf < 2; ++nf) {
                if (nf < nc) {
                    short8 bh = *(const short8*)(eph0 + (size_t)nf * 16 * 1024 + kk);
                    short8 bl = *(const short8*)(epl0 + (size_t)nf * 16 * 1024 + kk);
                    acc[nf] = MFMA16(ah, bh, acc[nf]);
                    acc[nf] = MFMA16(ah, bl, acc[nf]);
                    acc[nf] = MFMA16(al, bh, acc[nf]);
                }
            }
        }
        __syncthreads();
    }
    // dump score frags: row = lg*4 + reg, col = (nb+nf)*16 + lr
    #pragma unroll
    for (int nf = 0; nf < 2; ++nf)
        if (nf < nc) {
            #pragma unroll
            for (int reg = 0; reg < 4; ++reg)
                Ss[(lg * 4 + reg) * 113 + (nb + nf) * 16 + lr] = acc[nf][reg];
        }
    __syncthreads();
    // ---- softmax over 101 entities per row: 16 rows x 16 entity-groups
    int l = tid & 15, eg = tid >> 4;
    float h = hint[(size_t)b * L_ + l0 + l];
    float sc[7];
    #pragma unroll
    for (int j = 0; j < 7; ++j) {
        int e = eg + 16 * j;
        sc[j] = (e < E1_) ? (Ss[l * 113 + e] + h * ep_last[b * E1_ + e]) : -3.4e38f;
    }
    float mloc = -3.4e38f;
    #pragma unroll
    for (int j = 0; j < 7; ++j) mloc = fmaxf(mloc, sc[j]);
    red[l][eg] = mloc;
    __syncthreads();
    float m = red[l][0];
    #pragma unroll
    for (int k = 1; k < 16; ++k) m = fmaxf(m, red[l][k]);
    __syncthreads();
    float p[7];
    float sloc = 0.f;
    #pragma unroll
    for (int j = 0; j < 7; ++j) {
        p[j] = 0.f;
        if (eg + 16 * j < E1_) { p[j] = __expf(sc[j] - m); sloc += p[j]; }
    }
    red[l][eg] = sloc;
    __syncthreads();
    float ssum = 0.f;
    #pragma unroll
    for (int k = 0; k < 16; ++k) ssum += red[l][k];
    float inv = 1.f / ssum;
    bool valid = (l0 + l) < qn;
    float maskv = valid ? inv : 0.f;
    float* row = &co_att[((size_t)b * L_ + l0 + l) * E1_];
    #pragma unroll
    for (int j = 0; j < 7; ++j) {
        int e = eg + 16 * j;
        if (e < E1_) row[e] = p[j] * maskv;
    }
    // partial att: sum over this tile's valid rows (16-lane group reduce over l)
    #pragma unroll
    for (int j = 0; j < 7; ++j) {
        int e = eg + 16 * j;
        float v = (e < E1_) ? p[j] * maskv : 0.f;
        v += __shfl_xor(v, 1);  v += __shfl_xor(v, 2);
        v += __shfl_xor(v, 4);  v += __shfl_xor(v, 8);
        if ((tid & 15) == 0 && e < E1_)
            partial[((size_t)b * NT3_ + mt) * E1_ + e] = v;
    }
}

// ---------------- K4: att[b,e] = min(sum of partials, 1)
__global__ __launch_bounds__(256) void k_final(const float* __restrict__ partial,
                                               float* __restrict__ att) {
    int i = blockIdx.x * 256 + threadIdx.x;
    if (i >= B_ * E_) return;
    int b = i / E_, e = i % E_;
    float s = 0.f;
    #pragma unroll
    for (int k = 0; k < NT3_; ++k) s += partial[((size_t)b * NT3_ + k) * E1_ + e];
    att[i] = fminf(s, 1.f);
}

extern "C" void kernel_launch(void* const* d_in, const int* in_sizes, int n_in,
                              void* d_out, int out_size, void* d_ws, size_t ws_size,
                              hipStream_t stream) {
    const float* q_enc    = (const float*)d_in[0];
    const float* hint     = (const float*)d_in[1];
    const float* W        = (const float*)d_in[2];
    const float* bias     = (const float*)d_in[3];
    const float* none_ent = (const float*)d_in[4];
    const int*   qlen     = (const int*)d_in[5];
    const int*   ranges   = (const int*)d_in[6];

    float* att    = (float*)d_out;
    float* co_att = att + (size_t)B_ * E_;

    u16* enc_hi = (u16*)d_ws;
    u16* enc_lo = enc_hi + (size_t)M2P_ * 1024;
    u16* w_hi   = enc_lo + (size_t)M2P_ * 1024;
    u16* w_lo   = w_hi + (size_t)1024 * 1024;
    u16* ep_hi  = w_lo + (size_t)1024 * 1024;
    u16* ep_lo  = ep_hi + (size_t)M2P_ * 1024;
    float* ep_last = (float*)(ep_lo + (size_t)M2P_ * 1024);
    float* part    = ep_last + M2P_;

    k_prep<<<NPREP_, 256, 0, stream>>>(q_enc, none_ent, W, bias, ranges,
                                       enc_hi, enc_lo, w_hi, w_lo, ep_last, co_att);
    k_entproj<<<dim3(16, 52), 256, 0, stream>>>(enc_hi, enc_lo, w_hi, w_lo, bias, ep_hi, ep_lo);
    k_scores<<<B_ * NT3_, 256, 0, stream>>>(q_enc, hint, ep_hi, ep_lo, ep_last, qlen, co_att, part);
    k_final<<<13, 256, 0, stream>>>(part, att);
}

// Round 15
// 76.498 us; speedup vs baseline: 1.3002x; 1.1940x over previous
//
#include <hip/hip_runtime.h>
#include <hip/hip_bf16.h>

typedef unsigned short u16;
typedef __attribute__((ext_vector_type(8))) short short8;
typedef __attribute__((ext_vector_type(4))) float f32x4;

#define B_ 32
#define L_ 1024
#define D_ 1024
#define E_ 100
#define E1_ 101
#define M2_ (B_ * E1_)     // 3232 entity rows (incl. none-entity)
#define M2P_ 3328          // padded to 52*64 for MFMA tiles
#define QBLK_ 16           // rows per scores block
#define NT3_ 13            // ceil(Q_MAX=200 / 16) tiles that can contain valid rows
#define ZROW0_ (NT3_ * QBLK_)  // 208: first always-masked row
#define NZF_ 640               // zerofill blocks (20 per batch)
#define NPREP_ (M2_ + 1024 + NZF_)

#define MFMA16(a, b, c) __builtin_amdgcn_mfma_f32_16x16x32_bf16((a), (b), (c), 0, 0, 0)

__device__ __forceinline__ void split2(float x, u16& h, u16& l) {
    __hip_bfloat16 bh = __float2bfloat16(x);          // RN
    float r = x - __bfloat162float(bh);
    __hip_bfloat16 bl = __float2bfloat16(r);
    h = __builtin_bit_cast(u16, bh);
    l = __builtin_bit_cast(u16, bl);
}

// async global->LDS, 16B per lane; LDS dest = wave-uniform base + lane*16
__device__ __forceinline__ void gload16(const void* g, void* l) {
    __builtin_amdgcn_global_load_lds(
        (const __attribute__((address_space(1))) unsigned int*)g,
        (__attribute__((address_space(3))) unsigned int*)l, 16, 0, 0);
}

// ---------------- K1: flat fusion of [encode | wsplit | zerofill] (all independent)
__global__ __launch_bounds__(256) void k_prep(const float* __restrict__ q_enc,
                                              const float* __restrict__ none_ent,
                                              const float* __restrict__ W,
                                              const float* __restrict__ bias,
                                              const int* __restrict__ ranges,
                                              u16* __restrict__ enc_hi, u16* __restrict__ enc_lo,
                                              u16* __restrict__ w_hi, u16* __restrict__ w_lo,
                                              float* __restrict__ ep_last,
                                              float* __restrict__ co_att) {
    __shared__ float red4[4];
    int u = blockIdx.x;
    int t = threadIdx.x, c = t * 4;
    if (u < M2_) {
        // ---- encode unit: one (b, e) entity row
        int b = u / E1_, e = u - b * E1_;
        float4 acc;
        if (e == E_) {
            acc = *(const float4*)&none_ent[c];
        } else {
            acc = make_float4(0.f, 0.f, 0.f, 0.f);
            int r0 = ranges[(b * E_ + e) * 2 + 0];
            int r1 = ranges[(b * E_ + e) * 2 + 1];
            for (int l = r0 + 1; l < r1; ++l) {
                float4 v = *(const float4*)&q_enc[((size_t)b * L_ + l) * D_ + c];
                acc.x += v.x; acc.y += v.y; acc.z += v.z; acc.w += v.w;
            }
        }
        union { u16 uu[4]; float2 f; } ph, pl;
        split2(acc.x, ph.uu[0], pl.uu[0]); split2(acc.y, ph.uu[1], pl.uu[1]);
        split2(acc.z, ph.uu[2], pl.uu[2]); split2(acc.w, ph.uu[3], pl.uu[3]);
        *(float2*)&enc_hi[(size_t)u * 1024 + c] = ph.f;
        *(float2*)&enc_lo[(size_t)u * 1024 + c] = pl.f;
        const float* w1k = W + (size_t)1024 * 1024;
        float4 wv = *(const float4*)&w1k[c];
        float s = acc.x * wv.x + acc.y * wv.y + acc.z * wv.z + acc.w * wv.w;
        #pragma unroll
        for (int off = 32; off; off >>= 1) s += __shfl_down(s, off);
        if ((t & 63) == 0) red4[t >> 6] = s;
        __syncthreads();
        if (t == 0) ep_last[u] = red4[0] + red4[1] + red4[2] + red4[3] + bias[1024];
    } else if (u < M2_ + 1024) {
        // ---- wsplit unit: one W row
        int r = u - M2_;
        float4 v = *(const float4*)&W[(size_t)r * 1024 + c];
        union { u16 uu[4]; float2 f; } ph, pl;
        split2(v.x, ph.uu[0], pl.uu[0]); split2(v.y, ph.uu[1], pl.uu[1]);
        split2(v.z, ph.uu[2], pl.uu[2]); split2(v.w, ph.uu[3], pl.uu[3]);
        *(float2*)&w_hi[(size_t)r * 1024 + c] = ph.f;
        *(float2*)&w_lo[(size_t)r * 1024 + c] = pl.f;
    } else {
        // ---- zerofill unit: 1/20th of one batch's always-masked co_att rows
        int zu = u - M2_ - 1024;          // 0..639
        int b = zu / 20, part = zu % 20;
        float4* base = (float4*)&co_att[((size_t)b * L_ + ZROW0_) * E1_];
        const int n4 = (L_ - ZROW0_) * E1_ / 4;   // 816*101/4 = 20604
        float4 z = make_float4(0.f, 0.f, 0.f, 0.f);
        for (int i = part * 256 + t; i < n4; i += 20 * 256)
            base[i] = z;
    }
}

// ---------------- K2: ep = enc . W^T + bias, 3-term bf16 MFMA
// 64x64 tile -> grid (16,52) = 832 blocks, LDS 32KB, launch_bounds(256,4).
__global__ __launch_bounds__(256, 4) void k_entproj(const u16* __restrict__ A_hi, const u16* __restrict__ A_lo,
                                                    const u16* __restrict__ B_hi, const u16* __restrict__ B_lo,
                                                    const float* __restrict__ bias,
                                                    u16* __restrict__ ep_hi, u16* __restrict__ ep_lo) {
    __shared__ __attribute__((aligned(16))) u16 Ah[64 * 64], Al[64 * 64], Bh[64 * 64], Bl[64 * 64];
    int tid = threadIdx.x;
    int m0 = blockIdx.y * 64, n0 = blockIdx.x * 64;
    int w = tid >> 6, lane = tid & 63, lr = lane & 15, lg = lane >> 4;
    int wr = w >> 1, wc = w & 1;
    f32x4 zero = {0.f, 0.f, 0.f, 0.f};
    f32x4 acc[2][2] = {{zero, zero}, {zero, zero}};
    for (int k0 = 0; k0 < 1024; k0 += 64) {
        // 512 slots per array (64 rows x 8 sgroups); per wave 128 slots (2 j-iters)
        #pragma unroll
        for (int j = 0; j < 2; ++j) {
            int slot = w * 128 + j * 64 + lane;   // slot = r*8 + s
            int r = slot >> 3, s = slot & 7;
            int g = (s ^ (r & 7)) << 3;           // pre-swizzled source column group
            size_t ga = (size_t)(m0 + r) * 1024 + k0 + g;
            size_t gb = (size_t)(n0 + r) * 1024 + k0 + g;
            int ld = (w * 128 + j * 64) * 8;      // wave-uniform LDS base (u16 idx)
            gload16(&A_hi[ga], &Ah[ld]);
            gload16(&A_lo[ga], &Al[ld]);
            gload16(&B_hi[gb], &Bh[ld]);
            gload16(&B_lo[gb], &Bl[ld]);
        }
        __syncthreads();
        #pragma unroll
        for (int half = 0; half < 2; ++half) {
            int sk = half * 4 + lg;
            short8 a_h[2], a_l[2], b_h[2], b_l[2];
            #pragma unroll
            for (int mf = 0; mf < 2; ++mf) {
                int R = wr * 32 + mf * 16 + lr;
                int ad = R * 64 + ((sk ^ (R & 7)) << 3);
                a_h[mf] = __builtin_bit_cast(short8, *(const float4*)&Ah[ad]);
                a_l[mf] = __builtin_bit_cast(short8, *(const float4*)&Al[ad]);
            }
            #pragma unroll
            for (int nf = 0; nf < 2; ++nf) {
                int R = wc * 32 + nf * 16 + lr;
                int ad = R * 64 + ((sk ^ (R & 7)) << 3);
                b_h[nf] = __builtin_bit_cast(short8, *(const float4*)&Bh[ad]);
                b_l[nf] = __builtin_bit_cast(short8, *(const float4*)&Bl[ad]);
            }
            #pragma unroll
            for (int mf = 0; mf < 2; ++mf)
                #pragma unroll
                for (int nf = 0; nf < 2; ++nf) {
                    acc[mf][nf] = MFMA16(a_h[mf], b_h[nf], acc[mf][nf]);
                    acc[mf][nf] = MFMA16(a_h[mf], b_l[nf], acc[mf][nf]);
                    acc[mf][nf] = MFMA16(a_l[mf], b_h[nf], acc[mf][nf]);
                }
        }
        __syncthreads();
    }
    #pragma unroll
    for (int mf = 0; mf < 2; ++mf)
        #pragma unroll
        for (int nf = 0; nf < 2; ++nf)
            #pragma unroll
            for (int reg = 0; reg < 4; ++reg) {
                int m = m0 + wr * 32 + mf * 16 + lg * 4 + reg;
                if (m < M2_) {
                    int n = n0 + wc * 32 + nf * 16 + lr;
                    float v = acc[mf][nf][reg] + bias[n];
                    u16 h, l;
                    split2(v, h, l);
                    ep_hi[(size_t)m * 1024 + n] = h;
                    ep_lo[(size_t)m * 1024 + n] = l;
                }
            }
}

// ---------------- K3: scores (MFMA) + fused softmax + co_att writes
// flat grid 416: b = id&31, mt = id>>5  ->  XCD = id%8 = b%8: each batch's 13
// tiles (and its ep panel + q rows) pinned to one XCD's L2 (4 batches/XCD,
// ep working set 3.4 MB < 4 MB L2; 12 of 13 ep re-reads become L2 hits).
__global__ __launch_bounds__(256, 3) void k_scores(const float* __restrict__ q_enc,
                                                   const float* __restrict__ hint,
                                                   const u16* __restrict__ ep_hi, const u16* __restrict__ ep_lo,
                                                   const float* __restrict__ ep_last,
                                                   const int* __restrict__ qlen,
                                                   float* __restrict__ co_att,
                                                   float* __restrict__ partial) {
    __shared__ __attribute__((aligned(16))) u16 Ah[16 * 64], Al[16 * 64], Bh[128 * 64], Bl[128 * 64];
    __shared__ float Ss[16 * 113];
    __shared__ float red[QBLK_][16];
    int id = blockIdx.x;
    int b = id & 31, mt = id >> 5, l0 = mt * QBLK_;
    int tid = threadIdx.x;
    int qn = qlen[b];
    if (l0 >= qn) {
        // masked tile: zero co_att rows + zero partial
        float* base = &co_att[((size_t)b * L_ + l0) * E1_];
        float4 z = make_float4(0.f, 0.f, 0.f, 0.f);
        for (int i = tid; i < QBLK_ * E1_ / 4; i += 256)
            *(float4*)&base[i * 4] = z;
        for (int e = tid; e < E1_; e += 256)
            partial[((size_t)b * NT3_ + mt) * E1_ + e] = 0.f;
        return;
    }
    int w = tid >> 6, lane = tid & 63, lr = lane & 15, lg = lane >> 4;
    int nb = w * 2, nc = (w == 3) ? 1 : 2;    // frags nb..nb+nc-1
    int sb = w * 256;
    f32x4 zero = {0.f, 0.f, 0.f, 0.f};
    f32x4 acc[2] = {zero, zero};
    for (int k0 = 0; k0 < 1024; k0 += 64) {
        {   // B: 128 rows x 64 k via gload_lds (rows >100 finite garbage, masked later)
            #pragma unroll
            for (int j = 0; j < 4; ++j) {
                int slot = sb + j * 64 + lane;
                int r = slot >> 3, s = slot & 7;
                int g = (s ^ (r & 7)) << 3;
                size_t gb = ((size_t)b * E1_ + r) * 1024 + k0 + g;
                int ld = (sb + j * 64) * 8;
                gload16(&ep_hi[gb], &Bh[ld]);
                gload16(&ep_lo[gb], &Bl[ld]);
            }
        }
        if (tid < 128) {  // A: 16 rows x 64 k, split fp32 -> hi/lo on the fly
            int r = tid >> 3, s = tid & 7;
            const float* src = &q_enc[((size_t)b * L_ + l0 + r) * D_ + k0 + s * 8];
            float4 x0 = *(const float4*)src, x1 = *(const float4*)(src + 4);
            float xs[8] = {x0.x, x0.y, x0.z, x0.w, x1.x, x1.y, x1.z, x1.w};
            short8 hv, lv;
            #pragma unroll
            for (int j = 0; j < 8; ++j) {
                u16 hh, ll;
                split2(xs[j], hh, ll);
                hv[j] = (short)hh; lv[j] = (short)ll;
            }
            int dst = r * 64 + ((s ^ (r & 7)) << 3);
            *(float4*)&Ah[dst] = __builtin_bit_cast(float4, hv);
            *(float4*)&Al[dst] = __builtin_bit_cast(float4, lv);
        }
        __syncthreads();
        #pragma unroll
        for (int ks = 0; ks < 2; ++ks) {
            int sk = ks * 4 + lg;
            int adA = lr * 64 + ((sk ^ (lr & 7)) << 3);
            short8 ah = __builtin_bit_cast(short8, *(const float4*)&Ah[adA]);
            short8 al = __builtin_bit_cast(short8, *(const float4*)&Al[adA]);
            #pragma unroll
            for (int nf = 0; nf < 2; ++nf) {
                if (nf < nc) {
                    int rB = (nb + nf) * 16 + lr;
                    int adB = rB * 64 + ((sk ^ (rB & 7)) << 3);
                    short8 bh = __builtin_bit_cast(short8, *(const float4*)&Bh[adB]);
                    short8 bl = __builtin_bit_cast(short8, *(const float4*)&Bl[adB]);
                    acc[nf] = MFMA16(ah, bh, acc[nf]);
                    acc[nf] = MFMA16(ah, bl, acc[nf]);
                    acc[nf] = MFMA16(al, bh, acc[nf]);
                }
            }
        }
        __syncthreads();
    }
    // dump score frags: row = lg*4 + reg, col = (nb+nf)*16 + lr
    #pragma unroll
    for (int nf = 0; nf < 2; ++nf)
        if (nf < nc) {
            #pragma unroll
            for (int reg = 0; reg < 4; ++reg)
                Ss[(lg * 4 + reg) * 113 + (nb + nf) * 16 + lr] = acc[nf][reg];
        }
    __syncthreads();
    // ---- softmax over 101 entities per row: 16 rows x 16 entity-groups
    int l = tid & 15, eg = tid >> 4;
    float h = hint[(size_t)b * L_ + l0 + l];
    float sc[7];
    #pragma unroll
    for (int j = 0; j < 7; ++j) {
        int e = eg + 16 * j;
        sc[j] = (e < E1_) ? (Ss[l * 113 + e] + h * ep_last[b * E1_ + e]) : -3.4e38f;
    }
    float mloc = -3.4e38f;
    #pragma unroll
    for (int j = 0; j < 7; ++j) mloc = fmaxf(mloc, sc[j]);
    red[l][eg] = mloc;
    __syncthreads();
    float m = red[l][0];
    #pragma unroll
    for (int k = 1; k < 16; ++k) m = fmaxf(m, red[l][k]);
    __syncthreads();
    float p[7];
    float sloc = 0.f;
    #pragma unroll
    for (int j = 0; j < 7; ++j) {
        p[j] = 0.f;
        if (eg + 16 * j < E1_) { p[j] = __expf(sc[j] - m); sloc += p[j]; }
    }
    red[l][eg] = sloc;
    __syncthreads();
    float ssum = 0.f;
    #pragma unroll
    for (int k = 0; k < 16; ++k) ssum += red[l][k];
    float inv = 1.f / ssum;
    bool valid = (l0 + l) < qn;
    float maskv = valid ? inv : 0.f;
    float* row = &co_att[((size_t)b * L_ + l0 + l) * E1_];
    #pragma unroll
    for (int j = 0; j < 7; ++j) {
        int e = eg + 16 * j;
        if (e < E1_) row[e] = p[j] * maskv;
    }
    // partial att: sum over this tile's valid rows (16-lane group reduce over l)
    #pragma unroll
    for (int j = 0; j < 7; ++j) {
        int e = eg + 16 * j;
        float v = (e < E1_) ? p[j] * maskv : 0.f;
        v += __shfl_xor(v, 1);  v += __shfl_xor(v, 2);
        v += __shfl_xor(v, 4);  v += __shfl_xor(v, 8);
        if ((tid & 15) == 0 && e < E1_)
            partial[((size_t)b * NT3_ + mt) * E1_ + e] = v;
    }
}

// ---------------- K4: att[b,e] = min(sum of partials, 1)
__global__ __launch_bounds__(256) void k_final(const float* __restrict__ partial,
                                               float* __restrict__ att) {
    int i = blockIdx.x * 256 + threadIdx.x;
    if (i >= B_ * E_) return;
    int b = i / E_, e = i % E_;
    float s = 0.f;
    #pragma unroll
    for (int k = 0; k < NT3_; ++k) s += partial[((size_t)b * NT3_ + k) * E1_ + e];
    att[i] = fminf(s, 1.f);
}

extern "C" void kernel_launch(void* const* d_in, const int* in_sizes, int n_in,
                              void* d_out, int out_size, void* d_ws, size_t ws_size,
                              hipStream_t stream) {
    const float* q_enc    = (const float*)d_in[0];
    const float* hint     = (const float*)d_in[1];
    const float* W        = (const float*)d_in[2];
    const float* bias     = (const float*)d_in[3];
    const float* none_ent = (const float*)d_in[4];
    const int*   qlen     = (const int*)d_in[5];
    const int*   ranges   = (const int*)d_in[6];

    float* att    = (float*)d_out;
    float* co_att = att + (size_t)B_ * E_;

    u16* enc_hi = (u16*)d_ws;
    u16* enc_lo = enc_hi + (size_t)M2P_ * 1024;
    u16* w_hi   = enc_lo + (size_t)M2P_ * 1024;
    u16* w_lo   = w_hi + (size_t)1024 * 1024;
    u16* ep_hi  = w_lo + (size_t)1024 * 1024;
    u16* ep_lo  = ep_hi + (size_t)M2P_ * 1024;
    float* ep_last = (float*)(ep_lo + (size_t)M2P_ * 1024);
    float* part    = ep_last + M2P_;

    k_prep<<<NPREP_, 256, 0, stream>>>(q_enc, none_ent, W, bias, ranges,
                                       enc_hi, enc_lo, w_hi, w_lo, ep_last, co_att);
    k_entproj<<<dim3(16, 52), 256, 0, stream>>>(enc_hi, enc_lo, w_hi, w_lo, bias, ep_hi, ep_lo);
    k_scores<<<B_ * NT3_, 256, 0, stream>>>(q_enc, hint, ep_hi, ep_lo, ep_last, qlen, co_att, part);
    k_final<<<13, 256, 0, stream>>>(part, att);
}

// Round 16
// 73.965 us; speedup vs baseline: 1.3447x; 1.0342x over previous
//
#include <hip/hip_runtime.h>
#include <hip/hip_bf16.h>

typedef unsigned short u16;
typedef __attribute__((ext_vector_type(8))) short short8;
typedef __attribute__((ext_vector_type(4))) float f32x4;

#define B_ 32
#define L_ 1024
#define D_ 1024
#define E_ 100
#define E1_ 101
#define M2_ (B_ * E1_)     // 3232 entity rows (incl. none-entity)
#define M2P_ 3328          // padded to 52*64 for MFMA tiles
#define QBLK_ 16           // rows per scores block
#define NT3_ 13            // ceil(Q_MAX=200 / 16) tiles that can contain valid rows
#define ZROW0_ (NT3_ * QBLK_)  // 208: first always-masked row
#define NZF_ 640               // zerofill blocks (20 per batch)
#define NPREP_ (M2_ + 1024 + NZF_)
#define MT_PAD_ 56             // m-tiles padded to 56 (%8==0) for XCD-affine entproj grid

#define MFMA16(a, b, c) __builtin_amdgcn_mfma_f32_16x16x32_bf16((a), (b), (c), 0, 0, 0)

__device__ __forceinline__ void split2(float x, u16& h, u16& l) {
    __hip_bfloat16 bh = __float2bfloat16(x);          // RN
    float r = x - __bfloat162float(bh);
    __hip_bfloat16 bl = __float2bfloat16(r);
    h = __builtin_bit_cast(u16, bh);
    l = __builtin_bit_cast(u16, bl);
}

// async global->LDS, 16B per lane; LDS dest = wave-uniform base + lane*16
__device__ __forceinline__ void gload16(const void* g, void* l) {
    __builtin_amdgcn_global_load_lds(
        (const __attribute__((address_space(1))) unsigned int*)g,
        (__attribute__((address_space(3))) unsigned int*)l, 16, 0, 0);
}

// ---------------- K1: flat fusion of [encode | wsplit | zerofill] (all independent)
__global__ __launch_bounds__(256) void k_prep(const float* __restrict__ q_enc,
                                              const float* __restrict__ none_ent,
                                              const float* __restrict__ W,
                                              const float* __restrict__ bias,
                                              const int* __restrict__ ranges,
                                              u16* __restrict__ enc_hi, u16* __restrict__ enc_lo,
                                              u16* __restrict__ w_hi, u16* __restrict__ w_lo,
                                              float* __restrict__ ep_last,
                                              float* __restrict__ co_att) {
    __shared__ float red4[4];
    int u = blockIdx.x;
    int t = threadIdx.x, c = t * 4;
    if (u < M2_) {
        // ---- encode unit: one (b, e) entity row
        int b = u / E1_, e = u - b * E1_;
        float4 acc;
        if (e == E_) {
            acc = *(const float4*)&none_ent[c];
        } else {
            acc = make_float4(0.f, 0.f, 0.f, 0.f);
            int r0 = ranges[(b * E_ + e) * 2 + 0];
            int r1 = ranges[(b * E_ + e) * 2 + 1];
            for (int l = r0 + 1; l < r1; ++l) {
                float4 v = *(const float4*)&q_enc[((size_t)b * L_ + l) * D_ + c];
                acc.x += v.x; acc.y += v.y; acc.z += v.z; acc.w += v.w;
            }
        }
        union { u16 uu[4]; float2 f; } ph, pl;
        split2(acc.x, ph.uu[0], pl.uu[0]); split2(acc.y, ph.uu[1], pl.uu[1]);
        split2(acc.z, ph.uu[2], pl.uu[2]); split2(acc.w, ph.uu[3], pl.uu[3]);
        *(float2*)&enc_hi[(size_t)u * 1024 + c] = ph.f;
        *(float2*)&enc_lo[(size_t)u * 1024 + c] = pl.f;
        const float* w1k = W + (size_t)1024 * 1024;
        float4 wv = *(const float4*)&w1k[c];
        float s = acc.x * wv.x + acc.y * wv.y + acc.z * wv.z + acc.w * wv.w;
        #pragma unroll
        for (int off = 32; off; off >>= 1) s += __shfl_down(s, off);
        if ((t & 63) == 0) red4[t >> 6] = s;
        __syncthreads();
        if (t == 0) ep_last[u] = red4[0] + red4[1] + red4[2] + red4[3] + bias[1024];
    } else if (u < M2_ + 1024) {
        // ---- wsplit unit: one W row
        int r = u - M2_;
        float4 v = *(const float4*)&W[(size_t)r * 1024 + c];
        union { u16 uu[4]; float2 f; } ph, pl;
        split2(v.x, ph.uu[0], pl.uu[0]); split2(v.y, ph.uu[1], pl.uu[1]);
        split2(v.z, ph.uu[2], pl.uu[2]); split2(v.w, ph.uu[3], pl.uu[3]);
        *(float2*)&w_hi[(size_t)r * 1024 + c] = ph.f;
        *(float2*)&w_lo[(size_t)r * 1024 + c] = pl.f;
    } else {
        // ---- zerofill unit: 1/20th of one batch's always-masked co_att rows
        int zu = u - M2_ - 1024;          // 0..639
        int b = zu / 20, part = zu % 20;
        float4* base = (float4*)&co_att[((size_t)b * L_ + ZROW0_) * E1_];
        const int n4 = (L_ - ZROW0_) * E1_ / 4;   // 816*101/4 = 20604
        float4 z = make_float4(0.f, 0.f, 0.f, 0.f);
        for (int i = part * 256 + t; i < n4; i += 20 * 256)
            base[i] = z;
    }
}

// ---------------- K2: ep = enc . W^T + bias, 3-term bf16 MFMA
// 64x64 tile, flat grid 896: id = n_t*56 + m_t  ->  XCD = id%8 = m_t%8
// (56%8==0): each XCD owns 7 m-panels (1.8 MB A) -> A-tile re-reads become
// L2 hits instead of 8x-replicated L3 streams. m_t >= 52 pad tiles exit.
__global__ __launch_bounds__(256, 4) void k_entproj(const u16* __restrict__ A_hi, const u16* __restrict__ A_lo,
                                                    const u16* __restrict__ B_hi, const u16* __restrict__ B_lo,
                                                    const float* __restrict__ bias,
                                                    u16* __restrict__ ep_hi, u16* __restrict__ ep_lo) {
    __shared__ __attribute__((aligned(16))) u16 Ah[64 * 64], Al[64 * 64], Bh[64 * 64], Bl[64 * 64];
    int id = blockIdx.x;
    int n_t = id / MT_PAD_, m_t = id % MT_PAD_;
    if (m_t >= 52) return;                      // pad tile (uniform exit, pre-barrier)
    int tid = threadIdx.x;
    int m0 = m_t * 64, n0 = n_t * 64;
    int w = tid >> 6, lane = tid & 63, lr = lane & 15, lg = lane >> 4;
    int wr = w >> 1, wc = w & 1;
    f32x4 zero = {0.f, 0.f, 0.f, 0.f};
    f32x4 acc[2][2] = {{zero, zero}, {zero, zero}};
    for (int k0 = 0; k0 < 1024; k0 += 64) {
        // 512 slots per array (64 rows x 8 sgroups); per wave 128 slots (2 j-iters)
        #pragma unroll
        for (int j = 0; j < 2; ++j) {
            int slot = w * 128 + j * 64 + lane;   // slot = r*8 + s
            int r = slot >> 3, s = slot & 7;
            int g = (s ^ (r & 7)) << 3;           // pre-swizzled source column group
            size_t ga = (size_t)(m0 + r) * 1024 + k0 + g;
            size_t gb = (size_t)(n0 + r) * 1024 + k0 + g;
            int ld = (w * 128 + j * 64) * 8;      // wave-uniform LDS base (u16 idx)
            gload16(&A_hi[ga], &Ah[ld]);
            gload16(&A_lo[ga], &Al[ld]);
            gload16(&B_hi[gb], &Bh[ld]);
            gload16(&B_lo[gb], &Bl[ld]);
        }
        __syncthreads();
        #pragma unroll
        for (int half = 0; half < 2; ++half) {
            int sk = half * 4 + lg;
            short8 a_h[2], a_l[2], b_h[2], b_l[2];
            #pragma unroll
            for (int mf = 0; mf < 2; ++mf) {
                int R = wr * 32 + mf * 16 + lr;
                int ad = R * 64 + ((sk ^ (R & 7)) << 3);
                a_h[mf] = __builtin_bit_cast(short8, *(const float4*)&Ah[ad]);
                a_l[mf] = __builtin_bit_cast(short8, *(const float4*)&Al[ad]);
            }
            #pragma unroll
            for (int nf = 0; nf < 2; ++nf) {
                int R = wc * 32 + nf * 16 + lr;
                int ad = R * 64 + ((sk ^ (R & 7)) << 3);
                b_h[nf] = __builtin_bit_cast(short8, *(const float4*)&Bh[ad]);
                b_l[nf] = __builtin_bit_cast(short8, *(const float4*)&Bl[ad]);
            }
            #pragma unroll
            for (int mf = 0; mf < 2; ++mf)
                #pragma unroll
                for (int nf = 0; nf < 2; ++nf) {
                    acc[mf][nf] = MFMA16(a_h[mf], b_h[nf], acc[mf][nf]);
                    acc[mf][nf] = MFMA16(a_h[mf], b_l[nf], acc[mf][nf]);
                    acc[mf][nf] = MFMA16(a_l[mf], b_h[nf], acc[mf][nf]);
                }
        }
        __syncthreads();
    }
    #pragma unroll
    for (int mf = 0; mf < 2; ++mf)
        #pragma unroll
        for (int nf = 0; nf < 2; ++nf)
            #pragma unroll
            for (int reg = 0; reg < 4; ++reg) {
                int m = m0 + wr * 32 + mf * 16 + lg * 4 + reg;
                if (m < M2_) {
                    int n = n0 + wc * 32 + nf * 16 + lr;
                    float v = acc[mf][nf][reg] + bias[n];
                    u16 h, l;
                    split2(v, h, l);
                    ep_hi[(size_t)m * 1024 + n] = h;
                    ep_lo[(size_t)m * 1024 + n] = l;
                }
            }
}

// ---------------- K3: scores (MFMA) + fused softmax + co_att writes
// flat grid 416: b = id&31, mt = id>>5  ->  XCD = id%8 = b%8: each batch's 13
// tiles (and its ep panel + q rows) pinned to one XCD's L2 (4 batches/XCD,
// ep working set 3.4 MB < 4 MB L2; 12 of 13 ep re-reads become L2 hits).
__global__ __launch_bounds__(256, 3) void k_scores(const float* __restrict__ q_enc,
                                                   const float* __restrict__ hint,
                                                   const u16* __restrict__ ep_hi, const u16* __restrict__ ep_lo,
                                                   const float* __restrict__ ep_last,
                                                   const int* __restrict__ qlen,
                                                   float* __restrict__ co_att,
                                                   float* __restrict__ partial) {
    __shared__ __attribute__((aligned(16))) u16 Ah[16 * 64], Al[16 * 64], Bh[128 * 64], Bl[128 * 64];
    __shared__ float Ss[16 * 113];
    __shared__ float red[QBLK_][16];
    int id = blockIdx.x;
    int b = id & 31, mt = id >> 5, l0 = mt * QBLK_;
    int tid = threadIdx.x;
    int qn = qlen[b];
    if (l0 >= qn) {
        // masked tile: zero co_att rows + zero partial
        float* base = &co_att[((size_t)b * L_ + l0) * E1_];
        float4 z = make_float4(0.f, 0.f, 0.f, 0.f);
        for (int i = tid; i < QBLK_ * E1_ / 4; i += 256)
            *(float4*)&base[i * 4] = z;
        for (int e = tid; e < E1_; e += 256)
            partial[((size_t)b * NT3_ + mt) * E1_ + e] = 0.f;
        return;
    }
    int w = tid >> 6, lane = tid & 63, lr = lane & 15, lg = lane >> 4;
    int nb = w * 2, nc = (w == 3) ? 1 : 2;    // frags nb..nb+nc-1
    int sb = w * 256;
    f32x4 zero = {0.f, 0.f, 0.f, 0.f};
    f32x4 acc[2] = {zero, zero};
    for (int k0 = 0; k0 < 1024; k0 += 64) {
        {   // B: 128 rows x 64 k via gload_lds (rows >100 finite garbage, masked later)
            #pragma unroll
            for (int j = 0; j < 4; ++j) {
                int slot = sb + j * 64 + lane;
                int r = slot >> 3, s = slot & 7;
                int g = (s ^ (r & 7)) << 3;
                size_t gb = ((size_t)b * E1_ + r) * 1024 + k0 + g;
                int ld = (sb + j * 64) * 8;
                gload16(&ep_hi[gb], &Bh[ld]);
                gload16(&ep_lo[gb], &Bl[ld]);
            }
        }
        if (tid < 128) {  // A: 16 rows x 64 k, split fp32 -> hi/lo on the fly
            int r = tid >> 3, s = tid & 7;
            const float* src = &q_enc[((size_t)b * L_ + l0 + r) * D_ + k0 + s * 8];
            float4 x0 = *(const float4*)src, x1 = *(const float4*)(src + 4);
            float xs[8] = {x0.x, x0.y, x0.z, x0.w, x1.x, x1.y, x1.z, x1.w};
            short8 hv, lv;
            #pragma unroll
            for (int j = 0; j < 8; ++j) {
                u16 hh, ll;
                split2(xs[j], hh, ll);
                hv[j] = (short)hh; lv[j] = (short)ll;
            }
            int dst = r * 64 + ((s ^ (r & 7)) << 3);
            *(float4*)&Ah[dst] = __builtin_bit_cast(float4, hv);
            *(float4*)&Al[dst] = __builtin_bit_cast(float4, lv);
        }
        __syncthreads();
        #pragma unroll
        for (int ks = 0; ks < 2; ++ks) {
            int sk = ks * 4 + lg;
            int adA = lr * 64 + ((sk ^ (lr & 7)) << 3);
            short8 ah = __builtin_bit_cast(short8, *(const float4*)&Ah[adA]);
            short8 al = __builtin_bit_cast(short8, *(const float4*)&Al[adA]);
            #pragma unroll
            for (int nf = 0; nf < 2; ++nf) {
                if (nf < nc) {
                    int rB = (nb + nf) * 16 + lr;
                    int adB = rB * 64 + ((sk ^ (rB & 7)) << 3);
                    short8 bh = __builtin_bit_cast(short8, *(const float4*)&Bh[adB]);
                    short8 bl = __builtin_bit_cast(short8, *(const float4*)&Bl[adB]);
                    acc[nf] = MFMA16(ah, bh, acc[nf]);
                    acc[nf] = MFMA16(ah, bl, acc[nf]);
                    acc[nf] = MFMA16(al, bh, acc[nf]);
                }
            }
        }
        __syncthreads();
    }
    // dump score frags: row = lg*4 + reg, col = (nb+nf)*16 + lr
    #pragma unroll
    for (int nf = 0; nf < 2; ++nf)
        if (nf < nc) {
            #pragma unroll
            for (int reg = 0; reg < 4; ++reg)
                Ss[(lg * 4 + reg) * 113 + (nb + nf) * 16 + lr] = acc[nf][reg];
        }
    __syncthreads();
    // ---- softmax over 101 entities per row: 16 rows x 16 entity-groups
    int l = tid & 15, eg = tid >> 4;
    float h = hint[(size_t)b * L_ + l0 + l];
    float sc[7];
    #pragma unroll
    for (int j = 0; j < 7; ++j) {
        int e = eg + 16 * j;
        sc[j] = (e < E1_) ? (Ss[l * 113 + e] + h * ep_last[b * E1_ + e]) : -3.4e38f;
    }
    float mloc = -3.4e38f;
    #pragma unroll
    for (int j = 0; j < 7; ++j) mloc = fmaxf(mloc, sc[j]);
    red[l][eg] = mloc;
    __syncthreads();
    float m = red[l][0];
    #pragma unroll
    for (int k = 1; k < 16; ++k) m = fmaxf(m, red[l][k]);
    __syncthreads();
    float p[7];
    float sloc = 0.f;
    #pragma unroll
    for (int j = 0; j < 7; ++j) {
        p[j] = 0.f;
        if (eg + 16 * j < E1_) { p[j] = __expf(sc[j] - m); sloc += p[j]; }
    }
    red[l][eg] = sloc;
    __syncthreads();
    float ssum = 0.f;
    #pragma unroll
    for (int k = 0; k < 16; ++k) ssum += red[l][k];
    float inv = 1.f / ssum;
    bool valid = (l0 + l) < qn;
    float maskv = valid ? inv : 0.f;
    float* row = &co_att[((size_t)b * L_ + l0 + l) * E1_];
    #pragma unroll
    for (int j = 0; j < 7; ++j) {
        int e = eg + 16 * j;
        if (e < E1_) row[e] = p[j] * maskv;
    }
    // partial att: sum over this tile's valid rows (16-lane group reduce over l)
    #pragma unroll
    for (int j = 0; j < 7; ++j) {
        int e = eg + 16 * j;
        float v = (e < E1_) ? p[j] * maskv : 0.f;
        v += __shfl_xor(v, 1);  v += __shfl_xor(v, 2);
        v += __shfl_xor(v, 4);  v += __shfl_xor(v, 8);
        if ((tid & 15) == 0 && e < E1_)
            partial[((size_t)b * NT3_ + mt) * E1_ + e] = v;
    }
}

// ---------------- K4: att[b,e] = min(sum of partials, 1)
__global__ __launch_bounds__(256) void k_final(const float* __restrict__ partial,
                                               float* __restrict__ att) {
    int i = blockIdx.x * 256 + threadIdx.x;
    if (i >= B_ * E_) return;
    int b = i / E_, e = i % E_;
    float s = 0.f;
    #pragma unroll
    for (int k = 0; k < NT3_; ++k) s += partial[((size_t)b * NT3_ + k) * E1_ + e];
    att[i] = fminf(s, 1.f);
}

extern "C" void kernel_launch(void* const* d_in, const int* in_sizes, int n_in,
                              void* d_out, int out_size, void* d_ws, size_t ws_size,
                              hipStream_t stream) {
    const float* q_enc    = (const float*)d_in[0];
    const float* hint     = (const float*)d_in[1];
    const float* W        = (const float*)d_in[2];
    const float* bias     = (const float*)d_in[3];
    const float* none_ent = (const float*)d_in[4];
    const int*   qlen     = (const int*)d_in[5];
    const int*   ranges   = (const int*)d_in[6];

    float* att    = (float*)d_out;
    float* co_att = att + (size_t)B_ * E_;

    u16* enc_hi = (u16*)d_ws;
    u16* enc_lo = enc_hi + (size_t)M2P_ * 1024;
    u16* w_hi   = enc_lo + (size_t)M2P_ * 1024;
    u16* w_lo   = w_hi + (size_t)1024 * 1024;
    u16* ep_hi  = w_lo + (size_t)1024 * 1024;
    u16* ep_lo  = ep_hi + (size_t)M2P_ * 1024;
    float* ep_last = (float*)(ep_lo + (size_t)M2P_ * 1024);
    float* part    = ep_last + M2P_;

    k_prep<<<NPREP_, 256, 0, stream>>>(q_enc, none_ent, W, bias, ranges,
                                       enc_hi, enc_lo, w_hi, w_lo, ep_last, co_att);
    k_entproj<<<16 * MT_PAD_, 256, 0, stream>>>(enc_hi, enc_lo, w_hi, w_lo, bias, ep_hi, ep_lo);
    k_scores<<<B_ * NT3_, 256, 0, stream>>>(q_enc, hint, ep_hi, ep_lo, ep_last, qlen, co_att, part);
    k_final<<<13, 256, 0, stream>>>(part, att);
}

// Round 17
// 72.913 us; speedup vs baseline: 1.3641x; 1.0144x over previous
//
#include <hip/hip_runtime.h>
#include <hip/hip_bf16.h>

typedef unsigned short u16;
typedef __attribute__((ext_vector_type(8))) short short8;
typedef __attribute__((ext_vector_type(4))) float f32x4;

#define B_ 32
#define L_ 1024
#define D_ 1024
#define E_ 100
#define E1_ 101
#define M2_ (B_ * E1_)     // 3232 entity rows (incl. none-entity)
#define M2P_ 3328          // padded to 52*64 for MFMA tiles
#define QBLK_ 16           // rows per scores block
#define NT3_ 13            // ceil(Q_MAX=200 / 16) tiles that can contain valid rows
#define NTILES_ (L_ / QBLK_)   // 64 tiles per batch
#define NPREP_ (M2_ + 1024)    // encode + wsplit (zerofill moved to k_scores)
#define MT_PAD_ 56             // m-tiles padded to 56 (%8==0) for XCD-affine entproj grid

#define MFMA16(a, b, c) __builtin_amdgcn_mfma_f32_16x16x32_bf16((a), (b), (c), 0, 0, 0)

__device__ __forceinline__ void split2(float x, u16& h, u16& l) {
    __hip_bfloat16 bh = __float2bfloat16(x);          // RN
    float r = x - __bfloat162float(bh);
    __hip_bfloat16 bl = __float2bfloat16(r);
    h = __builtin_bit_cast(u16, bh);
    l = __builtin_bit_cast(u16, bl);
}

// async global->LDS, 16B per lane; LDS dest = wave-uniform base + lane*16
__device__ __forceinline__ void gload16(const void* g, void* l) {
    __builtin_amdgcn_global_load_lds(
        (const __attribute__((address_space(1))) unsigned int*)g,
        (__attribute__((address_space(3))) unsigned int*)l, 16, 0, 0);
}

// ---------------- K1: flat fusion of [encode | wsplit] (all independent)
__global__ __launch_bounds__(256) void k_prep(const float* __restrict__ q_enc,
                                              const float* __restrict__ none_ent,
                                              const float* __restrict__ W,
                                              const float* __restrict__ bias,
                                              const int* __restrict__ ranges,
                                              u16* __restrict__ enc_hi, u16* __restrict__ enc_lo,
                                              u16* __restrict__ w_hi, u16* __restrict__ w_lo,
                                              float* __restrict__ ep_last) {
    __shared__ float red4[4];
    int u = blockIdx.x;
    int t = threadIdx.x, c = t * 4;
    if (u < M2_) {
        // ---- encode unit: one (b, e) entity row
        int b = u / E1_, e = u - b * E1_;
        float4 acc;
        if (e == E_) {
            acc = *(const float4*)&none_ent[c];
        } else {
            acc = make_float4(0.f, 0.f, 0.f, 0.f);
            int r0 = ranges[(b * E_ + e) * 2 + 0];
            int r1 = ranges[(b * E_ + e) * 2 + 1];
            for (int l = r0 + 1; l < r1; ++l) {
                float4 v = *(const float4*)&q_enc[((size_t)b * L_ + l) * D_ + c];
                acc.x += v.x; acc.y += v.y; acc.z += v.z; acc.w += v.w;
            }
        }
        union { u16 uu[4]; float2 f; } ph, pl;
        split2(acc.x, ph.uu[0], pl.uu[0]); split2(acc.y, ph.uu[1], pl.uu[1]);
        split2(acc.z, ph.uu[2], pl.uu[2]); split2(acc.w, ph.uu[3], pl.uu[3]);
        *(float2*)&enc_hi[(size_t)u * 1024 + c] = ph.f;
        *(float2*)&enc_lo[(size_t)u * 1024 + c] = pl.f;
        const float* w1k = W + (size_t)1024 * 1024;
        float4 wv = *(const float4*)&w1k[c];
        float s = acc.x * wv.x + acc.y * wv.y + acc.z * wv.z + acc.w * wv.w;
        #pragma unroll
        for (int off = 32; off; off >>= 1) s += __shfl_down(s, off);
        if ((t & 63) == 0) red4[t >> 6] = s;
        __syncthreads();
        if (t == 0) ep_last[u] = red4[0] + red4[1] + red4[2] + red4[3] + bias[1024];
    } else {
        // ---- wsplit unit: one W row
        int r = u - M2_;
        float4 v = *(const float4*)&W[(size_t)r * 1024 + c];
        union { u16 uu[4]; float2 f; } ph, pl;
        split2(v.x, ph.uu[0], pl.uu[0]); split2(v.y, ph.uu[1], pl.uu[1]);
        split2(v.z, ph.uu[2], pl.uu[2]); split2(v.w, ph.uu[3], pl.uu[3]);
        *(float2*)&w_hi[(size_t)r * 1024 + c] = ph.f;
        *(float2*)&w_lo[(size_t)r * 1024 + c] = pl.f;
    }
}

// ---------------- K2: ep = enc . W^T + bias, 3-term bf16 MFMA
// 64x64 tile, flat grid 896: id = n_t*56 + m_t  ->  XCD = id%8 = m_t%8
// (56%8==0): each XCD owns 7 m-panels (1.8 MB A) -> A-tile re-reads become
// L2 hits instead of 8x-replicated L3 streams. m_t >= 52 pad tiles exit.
__global__ __launch_bounds__(256, 4) void k_entproj(const u16* __restrict__ A_hi, const u16* __restrict__ A_lo,
                                                    const u16* __restrict__ B_hi, const u16* __restrict__ B_lo,
                                                    const float* __restrict__ bias,
                                                    u16* __restrict__ ep_hi, u16* __restrict__ ep_lo) {
    __shared__ __attribute__((aligned(16))) u16 Ah[64 * 64], Al[64 * 64], Bh[64 * 64], Bl[64 * 64];
    int id = blockIdx.x;
    int n_t = id / MT_PAD_, m_t = id % MT_PAD_;
    if (m_t >= 52) return;                      // pad tile (uniform exit, pre-barrier)
    int tid = threadIdx.x;
    int m0 = m_t * 64, n0 = n_t * 64;
    int w = tid >> 6, lane = tid & 63, lr = lane & 15, lg = lane >> 4;
    int wr = w >> 1, wc = w & 1;
    f32x4 zero = {0.f, 0.f, 0.f, 0.f};
    f32x4 acc[2][2] = {{zero, zero}, {zero, zero}};
    for (int k0 = 0; k0 < 1024; k0 += 64) {
        // 512 slots per array (64 rows x 8 sgroups); per wave 128 slots (2 j-iters)
        #pragma unroll
        for (int j = 0; j < 2; ++j) {
            int slot = w * 128 + j * 64 + lane;   // slot = r*8 + s
            int r = slot >> 3, s = slot & 7;
            int g = (s ^ (r & 7)) << 3;           // pre-swizzled source column group
            size_t ga = (size_t)(m0 + r) * 1024 + k0 + g;
            size_t gb = (size_t)(n0 + r) * 1024 + k0 + g;
            int ld = (w * 128 + j * 64) * 8;      // wave-uniform LDS base (u16 idx)
            gload16(&A_hi[ga], &Ah[ld]);
            gload16(&A_lo[ga], &Al[ld]);
            gload16(&B_hi[gb], &Bh[ld]);
            gload16(&B_lo[gb], &Bl[ld]);
        }
        __syncthreads();
        #pragma unroll
        for (int half = 0; half < 2; ++half) {
            int sk = half * 4 + lg;
            short8 a_h[2], a_l[2], b_h[2], b_l[2];
            #pragma unroll
            for (int mf = 0; mf < 2; ++mf) {
                int R = wr * 32 + mf * 16 + lr;
                int ad = R * 64 + ((sk ^ (R & 7)) << 3);
                a_h[mf] = __builtin_bit_cast(short8, *(const float4*)&Ah[ad]);
                a_l[mf] = __builtin_bit_cast(short8, *(const float4*)&Al[ad]);
            }
            #pragma unroll
            for (int nf = 0; nf < 2; ++nf) {
                int R = wc * 32 + nf * 16 + lr;
                int ad = R * 64 + ((sk ^ (R & 7)) << 3);
                b_h[nf] = __builtin_bit_cast(short8, *(const float4*)&Bh[ad]);
                b_l[nf] = __builtin_bit_cast(short8, *(const float4*)&Bl[ad]);
            }
            #pragma unroll
            for (int mf = 0; mf < 2; ++mf)
                #pragma unroll
                for (int nf = 0; nf < 2; ++nf) {
                    acc[mf][nf] = MFMA16(a_h[mf], b_h[nf], acc[mf][nf]);
                    acc[mf][nf] = MFMA16(a_h[mf], b_l[nf], acc[mf][nf]);
                    acc[mf][nf] = MFMA16(a_l[mf], b_h[nf], acc[mf][nf]);
                }
        }
        __syncthreads();
    }
    #pragma unroll
    for (int mf = 0; mf < 2; ++mf)
        #pragma unroll
        for (int nf = 0; nf < 2; ++nf)
            #pragma unroll
            for (int reg = 0; reg < 4; ++reg) {
                int m = m0 + wr * 32 + mf * 16 + lg * 4 + reg;
                if (m < M2_) {
                    int n = n0 + wc * 32 + nf * 16 + lr;
                    float v = acc[mf][nf][reg] + bias[n];
                    u16 h, l;
                    split2(v, h, l);
                    ep_hi[(size_t)m * 1024 + n] = h;
                    ep_lo[(size_t)m * 1024 + n] = l;
                }
            }
}

// ---------------- K3: scores (MFMA) + fused softmax + co_att writes + tail zerofill
// flat grid 1024: b = id&31, mt = id>>5  ->  XCD = id%8 = b%8 (batch L2 affinity).
// ids < 416 (mt < 13): heavy score tiles; ids >= 416: light zerofill tiles
// (rows 208..1023 always masked) — dispatched after heavy, fill the CU tail.
__global__ __launch_bounds__(256, 3) void k_scores(const float* __restrict__ q_enc,
                                                   const float* __restrict__ hint,
                                                   const u16* __restrict__ ep_hi, const u16* __restrict__ ep_lo,
                                                   const float* __restrict__ ep_last,
                                                   const int* __restrict__ qlen,
                                                   float* __restrict__ co_att,
                                                   float* __restrict__ partial) {
    __shared__ __attribute__((aligned(16))) u16 Ah[16 * 64], Al[16 * 64], Bh[128 * 64], Bl[128 * 64];
    __shared__ float Ss[16 * 113];
    __shared__ float red[QBLK_][16];
    int id = blockIdx.x;
    int b = id & 31, mt = id >> 5, l0 = mt * QBLK_;
    int tid = threadIdx.x;
    if (mt >= NT3_) {
        // ---- light unit: zero one always-masked co_att tile (16 rows x 101)
        float* base = &co_att[((size_t)b * L_ + l0) * E1_];
        float4 z = make_float4(0.f, 0.f, 0.f, 0.f);
        for (int i = tid; i < QBLK_ * E1_ / 4; i += 256)
            *(float4*)&base[i * 4] = z;
        return;
    }
    int qn = qlen[b];
    if (l0 >= qn) {
        // masked heavy tile: zero co_att rows + zero partial
        float* base = &co_att[((size_t)b * L_ + l0) * E1_];
        float4 z = make_float4(0.f, 0.f, 0.f, 0.f);
        for (int i = tid; i < QBLK_ * E1_ / 4; i += 256)
            *(float4*)&base[i * 4] = z;
        for (int e = tid; e < E1_; e += 256)
            partial[((size_t)b * NT3_ + mt) * E1_ + e] = 0.f;
        return;
    }
    int w = tid >> 6, lane = tid & 63, lr = lane & 15, lg = lane >> 4;
    int nb = w * 2, nc = (w == 3) ? 1 : 2;    // frags nb..nb+nc-1
    int sb = w * 256;
    f32x4 zero = {0.f, 0.f, 0.f, 0.f};
    f32x4 acc[2] = {zero, zero};
    for (int k0 = 0; k0 < 1024; k0 += 64) {
        {   // B: 128 rows x 64 k via gload_lds (rows >100 finite garbage, masked later)
            #pragma unroll
            for (int j = 0; j < 4; ++j) {
                int slot = sb + j * 64 + lane;
                int r = slot >> 3, s = slot & 7;
                int g = (s ^ (r & 7)) << 3;
                size_t gb = ((size_t)b * E1_ + r) * 1024 + k0 + g;
                int ld = (sb + j * 64) * 8;
                gload16(&ep_hi[gb], &Bh[ld]);
                gload16(&ep_lo[gb], &Bl[ld]);
            }
        }
        if (tid < 128) {  // A: 16 rows x 64 k, split fp32 -> hi/lo on the fly
            int r = tid >> 3, s = tid & 7;
            const float* src = &q_enc[((size_t)b * L_ + l0 + r) * D_ + k0 + s * 8];
            float4 x0 = *(const float4*)src, x1 = *(const float4*)(src + 4);
            float xs[8] = {x0.x, x0.y, x0.z, x0.w, x1.x, x1.y, x1.z, x1.w};
            short8 hv, lv;
            #pragma unroll
            for (int j = 0; j < 8; ++j) {
                u16 hh, ll;
                split2(xs[j], hh, ll);
                hv[j] = (short)hh; lv[j] = (short)ll;
            }
            int dst = r * 64 + ((s ^ (r & 7)) << 3);
            *(float4*)&Ah[dst] = __builtin_bit_cast(float4, hv);
            *(float4*)&Al[dst] = __builtin_bit_cast(float4, lv);
        }
        __syncthreads();
        #pragma unroll
        for (int ks = 0; ks < 2; ++ks) {
            int sk = ks * 4 + lg;
            int adA = lr * 64 + ((sk ^ (lr & 7)) << 3);
            short8 ah = __builtin_bit_cast(short8, *(const float4*)&Ah[adA]);
            short8 al = __builtin_bit_cast(short8, *(const float4*)&Al[adA]);
            #pragma unroll
            for (int nf = 0; nf < 2; ++nf) {
                if (nf < nc) {
                    int rB = (nb + nf) * 16 + lr;
                    int adB = rB * 64 + ((sk ^ (rB & 7)) << 3);
                    short8 bh = __builtin_bit_cast(short8, *(const float4*)&Bh[adB]);
                    short8 bl = __builtin_bit_cast(short8, *(const float4*)&Bl[adB]);
                    acc[nf] = MFMA16(ah, bh, acc[nf]);
                    acc[nf] = MFMA16(ah, bl, acc[nf]);
                    acc[nf] = MFMA16(al, bh, acc[nf]);
                }
            }
        }
        __syncthreads();
    }
    // dump score frags: row = lg*4 + reg, col = (nb+nf)*16 + lr
    #pragma unroll
    for (int nf = 0; nf < 2; ++nf)
        if (nf < nc) {
            #pragma unroll
            for (int reg = 0; reg < 4; ++reg)
                Ss[(lg * 4 + reg) * 113 + (nb + nf) * 16 + lr] = acc[nf][reg];
        }
    __syncthreads();
    // ---- softmax over 101 entities per row: 16 rows x 16 entity-groups
    int l = tid & 15, eg = tid >> 4;
    float h = hint[(size_t)b * L_ + l0 + l];
    float sc[7];
    #pragma unroll
    for (int j = 0; j < 7; ++j) {
        int e = eg + 16 * j;
        sc[j] = (e < E1_) ? (Ss[l * 113 + e] + h * ep_last[b * E1_ + e]) : -3.4e38f;
    }
    float mloc = -3.4e38f;
    #pragma unroll
    for (int j = 0; j < 7; ++j) mloc = fmaxf(mloc, sc[j]);
    red[l][eg] = mloc;
    __syncthreads();
    float m = red[l][0];
    #pragma unroll
    for (int k = 1; k < 16; ++k) m = fmaxf(m, red[l][k]);
    __syncthreads();
    float p[7];
    float sloc = 0.f;
    #pragma unroll
    for (int j = 0; j < 7; ++j) {
        p[j] = 0.f;
        if (eg + 16 * j < E1_) { p[j] = __expf(sc[j] - m); sloc += p[j]; }
    }
    red[l][eg] = sloc;
    __syncthreads();
    float ssum = 0.f;
    #pragma unroll
    for (int k = 0; k < 16; ++k) ssum += red[l][k];
    float inv = 1.f / ssum;
    bool valid = (l0 + l) < qn;
    float maskv = valid ? inv : 0.f;
    float* row = &co_att[((size_t)b * L_ + l0 + l) * E1_];
    #pragma unroll
    for (int j = 0; j < 7; ++j) {
        int e = eg + 16 * j;
        if (e < E1_) row[e] = p[j] * maskv;
    }
    // partial att: sum over this tile's valid rows (16-lane group reduce over l)
    #pragma unroll
    for (int j = 0; j < 7; ++j) {
        int e = eg + 16 * j;
        float v = (e < E1_) ? p[j] * maskv : 0.f;
        v += __shfl_xor(v, 1);  v += __shfl_xor(v, 2);
        v += __shfl_xor(v, 4);  v += __shfl_xor(v, 8);
        if ((tid & 15) == 0 && e < E1_)
            partial[((size_t)b * NT3_ + mt) * E1_ + e] = v;
    }
}

// ---------------- K4: att[b,e] = min(sum of partials, 1)
__global__ __launch_bounds__(256) void k_final(const float* __restrict__ partial,
                                               float* __restrict__ att) {
    int i = blockIdx.x * 256 + threadIdx.x;
    if (i >= B_ * E_) return;
    int b = i / E_, e = i % E_;
    float s = 0.f;
    #pragma unroll
    for (int k = 0; k < NT3_; ++k) s += partial[((size_t)b * NT3_ + k) * E1_ + e];
    att[i] = fminf(s, 1.f);
}

extern "C" void kernel_launch(void* const* d_in, const int* in_sizes, int n_in,
                              void* d_out, int out_size, void* d_ws, size_t ws_size,
                              hipStream_t stream) {
    const float* q_enc    = (const float*)d_in[0];
    const float* hint     = (const float*)d_in[1];
    const float* W        = (const float*)d_in[2];
    const float* bias     = (const float*)d_in[3];
    const float* none_ent = (const float*)d_in[4];
    const int*   qlen     = (const int*)d_in[5];
    const int*   ranges   = (const int*)d_in[6];

    float* att    = (float*)d_out;
    float* co_att = att + (size_t)B_ * E_;

    u16* enc_hi = (u16*)d_ws;
    u16* enc_lo = enc_hi + (size_t)M2P_ * 1024;
    u16* w_hi   = enc_lo + (size_t)M2P_ * 1024;
    u16* w_lo   = w_hi + (size_t)1024 * 1024;
    u16* ep_hi  = w_lo + (size_t)1024 * 1024;
    u16* ep_lo  = ep_hi + (size_t)M2P_ * 1024;
    float* ep_last = (float*)(ep_lo + (size_t)M2P_ * 1024);
    float* part    = ep_last + M2P_;

    k_prep<<<NPREP_, 256, 0, stream>>>(q_enc, none_ent, W, bias, ranges,
                                       enc_hi, enc_lo, w_hi, w_lo, ep_last);
    k_entproj<<<16 * MT_PAD_, 256, 0, stream>>>(enc_hi, enc_lo, w_hi, w_lo, bias, ep_hi, ep_lo);
    k_scores<<<B_ * NTILES_, 256, 0, stream>>>(q_enc, hint, ep_hi, ep_lo, ep_last, qlen, co_att, part);
    k_final<<<13, 256, 0, stream>>>(part, att);
}